// Round 1
// 252.408 us; speedup vs baseline: 1.0015x; 1.0015x over previous
//
#include <hip/hip_runtime.h>
#include <stdint.h>

// ---------------------------------------------------------------------------
// GroupAttentionLayer: RF=16,STRIDE=16 windows tile the image exactly =>
//   yout = leaky(Q K^T / 16) V  (full dense attention per batch), then BN +
//   spatial softmax (mu/beta cancel; only a_c = g1/sqrt(var+eps) survives).
// B=4, P=4096 px/batch (T=16384 rows), C=256. Inputs fp32, OUTPUT fp32.
// R7: k_attn operands stored FRAGMENT-MAJOR in global so every MFMA fragment
// load is a lane-contiguous 1KB dwordx4 from L2.
// R8 (this round):
//   * BN stats for Q/K/V fused into k_qkv_gemm epilogue (k_stats1 removed:
//     saves a full 48MB re-read of Y + halves f64 atomic contention).
//   * GEMM writes Q/K planes FRAGMENT-MAJOR fp32 (YQK) so k_bn_qk becomes a
//     pure streaming kernel (coalesced 32B reads -> coalesced 16B writes);
//     previous k_bn_qk scattered 64x16B segments per wave (VMEM addr-path).
//     V plane stays row-major (Yv) for k_bn_v's LDS transpose.
//   * k_red: 128 blocks x 128 rows (f64 atomic contention 512 -> 128/addr).
//   * k_attn: s_setprio(1) around both MFMA phases (T5; two blocks/CU at
//     independent phases = the regime where setprio measured +4-7%).
//   Qf/Kf[((g*16+ks)*64+lane)*8+j] : row=g*32+(lane&31), ch=ks*16+(lane>>5)*8+j
//   Vf[((gc*256+kp)*64+lane)*8+j]  : ch=(gc&7)*32+(lane&31), key=kp*16+(lane>>5)*8+j
// ---------------------------------------------------------------------------

typedef __attribute__((ext_vector_type(8)))  short short8;   // 8 x bf16
typedef __attribute__((ext_vector_type(4)))  float f32x4;    // 16x16 acc
typedef __attribute__((ext_vector_type(16))) float f32x16;   // 32x32 acc
typedef __attribute__((ext_vector_type(4)))  unsigned short ushort4v;

#define ALPHA 0.3f
#define EPS   1e-3
#define NTOT  16384.0

__device__ __forceinline__ unsigned short f2bf(float f){
  unsigned u = __float_as_uint(f);
  u += 0x7FFFu + ((u>>16)&1u);          // RNE
  return (unsigned short)(u>>16);
}
__device__ __forceinline__ float lrelu(float x){ return x > 0.f ? x : ALPHA*x; }

// --------------------------------------------------------------- X fp32->bf16
__global__ __launch_bounds__(256)
void k_cvt(const float* __restrict__ X, unsigned short* __restrict__ Xb){
  int i = (blockIdx.x*256 + threadIdx.x)*4;
  float4 v = *(const float4*)(X + i);
  ushort4v o; o.x = f2bf(v.x); o.y = f2bf(v.y); o.z = f2bf(v.z); o.w = f2bf(v.w);
  *(ushort4v*)(Xb + i) = o;
}

// --------------------------------------------------------------- W transpose
__global__ __launch_bounds__(256)
void k_wtrans(const float* __restrict__ Wq,
              const float* __restrict__ Wk,
              const float* __restrict__ Wv,
              unsigned short* __restrict__ Wt){
  int o = blockIdx.x*256 + threadIdx.x;          // 0 .. 196608
  int p = o >> 16, rem = o & 65535;
  int j = rem >> 8, c = rem & 255;
  const float* W = (p==0) ? Wq : ((p==1) ? Wk : Wv);
  Wt[o] = f2bf(W[c*256 + j]);
}

// --------------------------------------------------------------- QKV GEMM
// Y[t][n] = sum_c Xb[t][c] * Wt[n][c],  t<16384, n<768.
// Q/K planes (nb<8) written fragment-major fp32 into YQK; V (nb>=8) row-major
// into Yv. BN stats (sum, sumsq per channel) fused into the epilogue.
__global__ __launch_bounds__(256)
void k_qkv_gemm(const unsigned short* __restrict__ X,
                const unsigned short* __restrict__ Wt,
                float* __restrict__ YQK, float* __restrict__ Yv,
                double* __restrict__ st){
  __shared__ __align__(16) unsigned short At[64*264];
  __shared__ __align__(16) unsigned short Bt[64*264];
  int tid = threadIdx.x;
  int mb = blockIdx.x, nb = blockIdx.y;
#pragma unroll
  for (int it = 0; it < 8; ++it){
    int s = it*256 + tid;
    int row = s >> 5, ch = s & 31;
    uint4 a = *(const uint4*)(X  + ((size_t)(mb*64 + row))*256 + ch*8);
    uint4 b = *(const uint4*)(Wt + ((size_t)(nb*64 + row))*256 + ch*8);
    *(uint4*)(At + row*264 + ch*8) = a;
    *(uint4*)(Bt + row*264 + ch*8) = b;
  }
  __syncthreads();
  int lane = tid & 63, wv = tid >> 6;
  int ln15 = lane & 15, quad = lane >> 4;
  int rw = (wv & 1)*32, cw = (wv >> 1)*32;     // 2x2 waves, 32x32 each
  f32x4 acc[2][2] = {};
#pragma unroll
  for (int ks = 0; ks < 8; ++ks){
    short8 afr[2], bfr[2];
#pragma unroll
    for (int mt = 0; mt < 2; ++mt){
      int r = rw + mt*16 + ln15;
      afr[mt] = *(const short8*)(At + r*264 + (ks*4+quad)*8);
    }
#pragma unroll
    for (int nt = 0; nt < 2; ++nt){
      int r = cw + nt*16 + ln15;
      bfr[nt] = *(const short8*)(Bt + r*264 + (ks*4+quad)*8);
    }
#pragma unroll
    for (int mt = 0; mt < 2; ++mt)
#pragma unroll
      for (int nt = 0; nt < 2; ++nt)
        acc[mt][nt] = __builtin_amdgcn_mfma_f32_16x16x32_bf16(afr[mt], bfr[nt], acc[mt][nt], 0,0,0);
  }
  // ---- per-lane column partials for BN stats (raw Y values)
  float ps[2] = {0.f, 0.f}, pq[2] = {0.f, 0.f};
#pragma unroll
  for (int mt = 0; mt < 2; ++mt)
#pragma unroll
    for (int nt = 0; nt < 2; ++nt)
#pragma unroll
      for (int r = 0; r < 4; ++r){
        float v = acc[mt][nt][r];
        ps[nt] += v; pq[nt] += v*v;
      }
  // ---- C-store
  if (nb < 8){
    // fragment-major fp32: chunk = (g*16+ks)*64 + l5c*32 + l31r, elem j
    int proj = nb >> 2;
    float* base = YQK + (size_t)proj*(16384*256);
    int l5c = ln15 >> 3, j = ln15 & 7;
#pragma unroll
    for (int mt = 0; mt < 2; ++mt){
      int g = (mb*64 + rw + mt*16) >> 5;
      int l31r0 = ((rw + mt*16) & 31) + quad*4;
#pragma unroll
      for (int nt = 0; nt < 2; ++nt){
        int ks2 = ((nb & 3)*64 + cw + nt*16) >> 4;
#pragma unroll
        for (int r = 0; r < 4; ++r){
          size_t chunk = (size_t)((g*16 + ks2)*64 + l5c*32 + l31r0 + r);
          base[chunk*8 + j] = acc[mt][nt][r];
        }
      }
    }
  } else {
    int vc0 = (nb - 8)*64 + cw;
#pragma unroll
    for (int mt = 0; mt < 2; ++mt)
#pragma unroll
      for (int nt = 0; nt < 2; ++nt)
#pragma unroll
        for (int r = 0; r < 4; ++r){
          int row = mb*64 + rw + mt*16 + quad*4 + r;
          Yv[(size_t)row*256 + vc0 + nt*16 + ln15] = acc[mt][nt][r];
        }
  }
  // ---- stats reduce: LDS (reuse At) then one f64 atomic pair per channel
  __syncthreads();                       // everyone done reading At/Bt
  float* red = (float*)At;               // [0..64) sum, [64..128) sumsq
  if (tid < 128) red[tid] = 0.f;
  __syncthreads();
#pragma unroll
  for (int nt = 0; nt < 2; ++nt){
    int colL = cw + nt*16 + ln15;        // 0..63
    atomicAdd(&red[colL],      ps[nt]);
    atomicAdd(&red[64 + colL], pq[nt]);
  }
  __syncthreads();
  if (tid < 64){
    int cc = nb*64 + tid;                // global channel 0..767
    atomicAdd(&st[cc],       (double)red[tid]);
    atomicAdd(&st[768 + cc], (double)red[64 + tid]);
  }
}

// --------------------------------------------------------------- BN coefs
// scv/shv[cc]: y_norm = y*scv + shv, cc in [0,768) = Q|K|V channels
__global__ __launch_bounds__(256)
void k_coef(const double* __restrict__ st,
            const float* __restrict__ gq, const float* __restrict__ bq,
            const float* __restrict__ gk, const float* __restrict__ bk,
            const float* __restrict__ gv, const float* __restrict__ bv,
            float* __restrict__ scv, float* __restrict__ shv){
  int cc = blockIdx.x*256 + threadIdx.x;   // 0..767
  int proj = cc >> 8, c = cc & 255;
  double mu  = st[cc]     * (1.0/NTOT);
  double var = st[768+cc] * (1.0/NTOT) - mu*mu;
  double g = (proj==0) ? gq[c] : (proj==1) ? gk[c] : gv[c];
  double b = (proj==0) ? bq[c] : (proj==1) ? bk[c] : bv[c];
  double sc = g / sqrt(var + EPS);
  scv[cc] = (float)sc;
  shv[cc] = (float)(b - mu*sc);
}

// --------------------------------------------------------------- BN+leaky Q,K
// pure streaming: YQK is already fragment-major fp32; apply BN+leaky, cast,
// write Qf/Kf at the identical chunk index. Fully coalesced both sides.
__global__ __launch_bounds__(256)
void k_bn_qk(const float* __restrict__ YQK,
             const float* __restrict__ scv, const float* __restrict__ shv,
             unsigned short* __restrict__ Qf, unsigned short* __restrict__ Kf){
  int oc = blockIdx.x*256 + threadIdx.x;      // 0..1048575 chunks of 8
  int proj = oc >> 19;
  int rest = oc & 524287;
  int ks = (rest >> 6) & 15, l5c = (rest >> 5) & 1;
  int ch0 = ks*16 + l5c*8;
  const float* src = YQK + (size_t)oc*8;
  float4 v0 = *(const float4*)(src);
  float4 v1 = *(const float4*)(src + 4);
  const float* sc = scv + proj*256 + ch0;
  const float* sh = shv + proj*256 + ch0;
  unsigned short r[8];
  r[0]=f2bf(lrelu(v0.x*sc[0]+sh[0])); r[1]=f2bf(lrelu(v0.y*sc[1]+sh[1]));
  r[2]=f2bf(lrelu(v0.z*sc[2]+sh[2])); r[3]=f2bf(lrelu(v0.w*sc[3]+sh[3]));
  r[4]=f2bf(lrelu(v1.x*sc[4]+sh[4])); r[5]=f2bf(lrelu(v1.y*sc[5]+sh[5]));
  r[6]=f2bf(lrelu(v1.z*sc[6]+sh[6])); r[7]=f2bf(lrelu(v1.w*sc[7]+sh[7]));
  uint4 u;
  u.x = (unsigned)r[0] | ((unsigned)r[1]<<16);
  u.y = (unsigned)r[2] | ((unsigned)r[3]<<16);
  u.z = (unsigned)r[4] | ((unsigned)r[5]<<16);
  u.w = (unsigned)r[6] | ((unsigned)r[7]<<16);
  *(uint4*)((proj ? Kf : Qf) + (size_t)rest*8) = u;
}

// --------------------------------------------------------------- BN+leaky Vf
// fragment-major V^T via LDS tile transpose; V plane now row-major [t][256]
__global__ __launch_bounds__(256)
void k_bn_v(const float* __restrict__ Yv,
            const float* __restrict__ scv, const float* __restrict__ shv,
            unsigned short* __restrict__ Vf){
  __shared__ unsigned short tile[64][66];      // [pixelLocal][chLocal]
  int tid = threadIdx.x;
  int pt = blockIdx.x, ct = blockIdx.y, b = blockIdx.z;
  int cl = tid & 63, rq = tid >> 6;
  int c  = ct*64 + cl;
  float sc = scv[512 + c], sh = shv[512 + c];
#pragma unroll 4
  for (int k = 0; k < 16; ++k){
    int r = k*4 + rq;
    size_t t = (size_t)b*4096 + pt*64 + r;
    float v = Yv[t*256 + c];
    tile[r][cl] = f2bf(lrelu(v*sc + sh));
  }
  __syncthreads();
#pragma unroll
  for (int it = 0; it < 2; ++it){
    int m = it*256 + tid;                      // 512 chunks of 8 keys
    int c2 = m >> 3, kg = m & 7;
    int ch = ct*64 + c2;
    int gc = b*8 + (ch >> 5), l31c = ch & 31;
    int kp = pt*4 + (kg >> 1), l5k = kg & 1;
    unsigned short r0 = tile[kg*8+0][c2], r1 = tile[kg*8+1][c2];
    unsigned short r2 = tile[kg*8+2][c2], r3 = tile[kg*8+3][c2];
    unsigned short r4 = tile[kg*8+4][c2], r5 = tile[kg*8+5][c2];
    unsigned short r6 = tile[kg*8+6][c2], r7 = tile[kg*8+7][c2];
    uint4 u;
    u.x = (unsigned)r0 | ((unsigned)r1<<16);
    u.y = (unsigned)r2 | ((unsigned)r3<<16);
    u.z = (unsigned)r4 | ((unsigned)r5<<16);
    u.w = (unsigned)r6 | ((unsigned)r7<<16);
    *(uint4*)(Vf + ((size_t)((gc*256 + kp)*64 + l5k*32 + l31c))*8) = u;
  }
}

// --------------------------------------------------------------- attention
// 512 blocks x 512 threads. blk>>3 = q-tile (64 rows), blk&7 = (b,half) ->
// XCD-pinned (round-robin dispatch) so each XCD's L2 holds its 2MB K/V.
// 8 iters of BK=256 keys, 2 barriers/iter. All global fragment loads are
// lane-contiguous 1KB (fragment-major layouts). Wave w: phase1 owns key
// group w*32 (computes both 32-row halves = 2 chains, no duplicate K reads);
// phase2 owns channels w*32..+32 (2 row-chain accumulators).
// setprio(1) wraps the MFMA phases (prio 0 over the VALU S-convert) so the
// CU scheduler favors MFMA-issuing waves of whichever block is in-phase.
__global__ __launch_bounds__(512, 4)
void k_attn(const unsigned short* __restrict__ Qf,
            const unsigned short* __restrict__ Kf,
            const unsigned short* __restrict__ Vf,
            float* __restrict__ P0, float* __restrict__ P1){
  __shared__ __align__(16) unsigned short Ql[64*256];   // frag-major Q tile
  __shared__ __align__(16) unsigned short Sl[64*264];   // [q][key] padded
  int tid = threadIdx.x;
  int blk = blockIdx.x;
  int qt = blk >> 3, combo = blk & 7;
  int b = combo >> 1, half = combo & 1;
  int q0 = qt*64;
  int lane = tid & 63, w = tid >> 6;
  int l31 = lane & 31, l5 = lane >> 5;
  float* P = half ? P1 : P0;

  // stage Q tile: contiguous 32KB copy (fragment-major, identity layout)
  int gq0 = b*128 + qt*2;
  {
    const uint4* src = (const uint4*)(Qf + (size_t)gq0*8192);
    uint4* dst = (uint4*)Ql;
#pragma unroll
    for (int it = 0; it < 4; ++it) dst[it*512 + tid] = src[it*512 + tid];
  }
  __syncthreads();

  f32x16 acc2[2] = {};
  // K frags: wave w owns keys [w*32, w*32+32) of each BK=256 chunk
  int gk0 = b*128 + half*64 + w;               // + kt*8 per iter
  const unsigned short* kb = Kf + (size_t)gk0*8192 + lane*8;
  // V frags: wave w owns channels [w*32, w*32+32)
  const unsigned short* vb = Vf + ((size_t)((b*8 + w)*256 + half*128))*512 + lane*8;
  const unsigned short* qa0 = Ql + lane*8;            // mloc 0, + ks*512
  const unsigned short* qa1 = Ql + 16*512 + lane*8;   // mloc 1

  for (int kt = 0; kt < 8; ++kt){
    // phase 1: S[0..64)[w*32..+32) over K=256, two independent row chains
    f32x16 a1[2] = {};
    const unsigned short* kbt = kb + (size_t)kt*8*8192;
    __builtin_amdgcn_s_setprio(1);
#pragma unroll
    for (int ks = 0; ks < 16; ++ks){
      short8 kf = *(const short8*)(kbt + ks*512);
      short8 q0v = *(const short8*)(qa0 + ks*512);
      short8 q1v = *(const short8*)(qa1 + ks*512);
      a1[0] = __builtin_amdgcn_mfma_f32_32x32x16_bf16(q0v, kf, a1[0], 0, 0, 0);
      a1[1] = __builtin_amdgcn_mfma_f32_32x32x16_bf16(q1v, kf, a1[1], 0, 0, 0);
    }
    __builtin_amdgcn_s_setprio(0);
    __syncthreads();     // B0: all waves done reading Sl of iter kt-1
#pragma unroll
    for (int reg = 0; reg < 16; ++reg){
      int rloc = (reg & 3) + 8*(reg >> 2) + 4*l5;
      Sl[rloc*264 + w*32 + l31]        = f2bf(lrelu(a1[0][reg]*0.0625f));
      Sl[(32 + rloc)*264 + w*32 + l31] = f2bf(lrelu(a1[1][reg]*0.0625f));
    }
    __syncthreads();     // B1: S visible
    // phase 2: acc2 += S[64x256] . V^T[32ch][256keys]
    const unsigned short* vbt = vb + (size_t)kt*16*512;
    __builtin_amdgcn_s_setprio(1);
#pragma unroll
    for (int kk = 0; kk < 16; ++kk){
      short8 vf = *(const short8*)(vbt + kk*512);
      short8 s0 = *(const short8*)(Sl + (     l31)*264 + kk*16 + l5*8);
      short8 s1 = *(const short8*)(Sl + (32 + l31)*264 + kk*16 + l5*8);
      acc2[0] = __builtin_amdgcn_mfma_f32_32x32x16_bf16(s0, vf, acc2[0], 0, 0, 0);
      acc2[1] = __builtin_amdgcn_mfma_f32_32x32x16_bf16(s1, vf, acc2[1], 0, 0, 0);
    }
    __builtin_amdgcn_s_setprio(0);
  }
#pragma unroll
  for (int c = 0; c < 2; ++c)
#pragma unroll
    for (int reg = 0; reg < 16; ++reg){
      int row = q0 + c*32 + (reg & 3) + 8*(reg >> 2) + 4*l5;
      P[((size_t)b*4096 + row)*256 + w*32 + l31] = acc2[c][reg];
    }
}

// ------------------------------------------------- partial reduce + BN stats
// 128 blocks x 128 rows: same traffic, 4x fewer conflicting f64 atomics/addr
__global__ __launch_bounds__(256)
void k_red(const float* __restrict__ P0, const float* __restrict__ P1,
           float* __restrict__ yout, double* __restrict__ st){
  int tid = threadIdx.x;
  int r0 = blockIdx.x*128;
  double sum = 0, sq = 0;
#pragma unroll 4
  for (int r = 0; r < 128; ++r){
    size_t idx = (size_t)(r0 + r)*256 + tid;
    float v = P0[idx] + P1[idx];
    yout[idx] = v;
    sum += v; sq += (double)v*v;
  }
  atomicAdd(&st[1536 + tid], sum);
  atomicAdd(&st[1792 + tid], sq);
}

// --------------------------------------------------------------- softmax
// BN => args are z-scores: no max pass needed; shift by a*mu.
__global__ __launch_bounds__(256)
void k_soft1(const float* __restrict__ yout, const double* __restrict__ st,
             const float* __restrict__ g1, float* __restrict__ sums){
  __shared__ float red[256];
  __shared__ float sA[64], sK[64];
  int tid = threadIdx.x;
  int chunk = blockIdx.x, ct = blockIdx.y, b = blockIdx.z;
  int cl = tid & 63, pg = tid >> 6;
  int c = ct*64 + cl;
  if (tid < 64){
    int cc = ct*64 + tid;
    double mu  = st[1536 + cc]*(1.0/NTOT);
    double var = st[1792 + cc]*(1.0/NTOT) - mu*mu;
    double a = g1[cc] / sqrt(var + EPS);
    sA[tid] = (float)a;
    sK[tid] = (float)(a*mu);
  }
  __syncthreads();
  float a = sA[cl], K = sK[cl];
  float s = 0.f;
  const float* base = yout + ((size_t)b*4096 + chunk*256)*256 + c;
#pragma unroll 4
  for (int k = 0; k < 64; ++k){
    float v = base[(size_t)(pg + k*4)*256];
    s += __expf(v*a - K);
  }
  red[tid] = s;
  __syncthreads();
  if (tid < 64){
    float tot = red[tid] + red[64+tid] + red[128+tid] + red[192+tid];
    atomicAdd(&sums[b*256 + ct*64 + tid], tot);
  }
}

__global__ __launch_bounds__(256)
void k_soft2(const float* __restrict__ yout, const double* __restrict__ st,
             const float* __restrict__ g1, const float* __restrict__ sums,
             float* __restrict__ out){
  __shared__ float sA[64], sK[64], sR[64];
  int tid = threadIdx.x;
  int chunk = blockIdx.x, ct = blockIdx.y, b = blockIdx.z;
  int cl = tid & 63, pg = tid >> 6;
  int c = ct*64 + cl;
  if (tid < 64){
    int cc = ct*64 + tid;
    double mu  = st[1536 + cc]*(1.0/NTOT);
    double var = st[1792 + cc]*(1.0/NTOT) - mu*mu;
    double a = g1[cc] / sqrt(var + EPS);
    sA[tid] = (float)a;
    sK[tid] = (float)(a*mu);
    sR[tid] = 1.f / sums[b*256 + cc];
  }
  __syncthreads();
  float a = sA[cl], K = sK[cl], rl = sR[cl];
  const float* base = yout + ((size_t)b*4096 + chunk*256)*256 + c;
  float* obase = out + ((size_t)b*4096 + chunk*256)*256 + c;
#pragma unroll 4
  for (int k = 0; k < 64; ++k){
    size_t idx = (size_t)(pg + k*4)*256;
    obase[idx] = __expf(base[idx]*a - K) * rl;
  }
}

// ---------------------------------------------------------------------------
extern "C" void kernel_launch(void* const* d_in, const int* in_sizes, int n_in,
                              void* d_out, int out_size, void* d_ws, size_t ws_size,
                              hipStream_t stream){
  (void)in_sizes; (void)n_in; (void)out_size; (void)ws_size;
  const float* X  = (const float*)d_in[0];
  const float* Wq = (const float*)d_in[1];
  const float* gq = (const float*)d_in[2];
  const float* bq = (const float*)d_in[3];
  const float* Wk = (const float*)d_in[4];
  const float* gk = (const float*)d_in[5];
  const float* bk = (const float*)d_in[6];
  const float* Wv = (const float*)d_in[7];
  const float* gv = (const float*)d_in[8];
  const float* bv = (const float*)d_in[9];
  const float* g1 = (const float*)d_in[10];
  // d_in[11] = b1: cancels inside the spatial softmax

  char* ws = (char*)d_ws;
  double*         st   = (double*)ws;                        // 2048 f64 (16KB)
  float*          sums = (float*)(ws + 16384);               // 4KB
  float*          scv  = (float*)(ws + 20480);               // 768 f32
  float*          shv  = (float*)(ws + 23552);               // 768 f32
  unsigned short* Wt   = (unsigned short*)(ws + 26624);      // 768x256 bf16
  unsigned short* Xb   = (unsigned short*)(ws + 419840);     // 16384x256 bf16
  float*          YQK  = (float*)(ws + 8808448);             // 2x16384x256 f32 (frag-major)
  float*          Yv   = (float*)(ws + 42362880);            // 16384x256 f32 row-major
  unsigned short* Kf   = (unsigned short*)(ws + 59140096);   // frag-major 8MB
  unsigned short* Vf   = (unsigned short*)(ws + 67528704);   // frag-major 8MB
  // overlays: Qf on Xb (dead after GEMM); P0|P1 on YQK (dead after bn_qk);
  // yout on Yv (dead after bn_v)
  unsigned short* Qf   = Xb;
  float*          P0   = YQK;
  float*          P1   = (float*)((char*)YQK + 16777216);
  float*          yo   = Yv;

  hipMemsetAsync(st, 0, 20480, stream);
  k_cvt     <<<4096, 256, 0, stream>>>(X, Xb);
  k_wtrans  <<<768, 256, 0, stream>>>(Wq, Wk, Wv, Wt);
  k_qkv_gemm<<<dim3(256,12), 256, 0, stream>>>(Xb, Wt, YQK, Yv, st);
  k_coef    <<<3, 256, 0, stream>>>(st, gq, bq, gk, bk, gv, bv, scv, shv);
  k_bn_qk   <<<4096, 256, 0, stream>>>(YQK, scv, shv, Qf, Kf);
  k_bn_v    <<<dim3(64,4,4), 256, 0, stream>>>(Yv, scv, shv, Vf);
  k_attn    <<<512, 512, 0, stream>>>(Qf, Kf, Vf, P0, P1);
  k_red     <<<128, 256, 0, stream>>>(P0, P1, yo, st);
  k_soft1   <<<dim3(16,4,4), 256, 0, stream>>>(yo, st, g1, sums);
  k_soft2   <<<dim3(16,4,4), 256, 0, stream>>>(yo, st, g1, sums, (float*)d_out);
}

// Round 2
// 251.214 us; speedup vs baseline: 1.0063x; 1.0047x over previous
//
#include <hip/hip_runtime.h>
#include <stdint.h>

// ---------------------------------------------------------------------------
// GroupAttentionLayer: RF=16,STRIDE=16 windows tile the image exactly =>
//   yout = leaky(Q K^T / 16) V  (full dense attention per batch), then BN +
//   spatial softmax (mu/beta cancel; only a_c = g1/sqrt(var+eps) survives).
// B=4, P=4096 px/batch (T=16384 rows), C=256. Inputs fp32, OUTPUT fp32.
// R7: k_attn operands stored FRAGMENT-MAJOR in global so every MFMA fragment
//     load is a lane-contiguous 1KB dwordx4 from L2.
// R8: BN stats fused into GEMM epilogue; GEMM writes Q/K frag-major fp32 so
//     bn is pure streaming; setprio(1) around attn MFMA phases (+7%).
// R9 (this round):
//   * Pipeline 11 -> 7 dispatches: k_prep = cvt + wtrans + ws-zero (memset
//     dropped); k_coef eliminated (bn blocks compute coefs inline from st);
//     k_bn = bn_qk + bn_v merged.   Rationale: serialized short kernels pay
//     ~5-10us each in launch/ramp on 256 CUs.
//   * k_red restored to 512 blocks x 32 rows (128-block version left half
//     the CUs idle on a 48MB pass -- round-1 regression).
//   * 1/16 score scale folded into Q's BN coefs (exact: exponent shift),
//     removing 32 v_mul per kt*wave in k_attn; lrelu = fmaxf(x,.3x).
//   Qf/Kf[((g*16+ks)*64+lane)*8+j] : row=g*32+(lane&31), ch=ks*16+(lane>>5)*8+j
//   Vf[((gc*256+kp)*64+lane)*8+j]  : ch=(gc&7)*32+(lane&31), key=kp*16+(lane>>5)*8+j
// ---------------------------------------------------------------------------

typedef __attribute__((ext_vector_type(8)))  short short8;   // 8 x bf16
typedef __attribute__((ext_vector_type(4)))  float f32x4;    // 16x16 acc
typedef __attribute__((ext_vector_type(16))) float f32x16;   // 32x32 acc
typedef __attribute__((ext_vector_type(4)))  unsigned short ushort4v;

#define ALPHA 0.3f
#define EPS   1e-3
#define NTOT  16384.0

__device__ __forceinline__ unsigned short f2bf(float f){
  unsigned u = __float_as_uint(f);
  u += 0x7FFFu + ((u>>16)&1u);          // RNE
  return (unsigned short)(u>>16);
}
__device__ __forceinline__ float lrelu(float x){ return fmaxf(x, ALPHA*x); }

// ------------------------------------------------- prep: cvt + wtrans + zero
// blocks [0,4096): X fp32->bf16.  blocks [4096,4864): W transpose->bf16;
// first 20 of those also zero st/sums (5120 f32 = 20480B).
__global__ __launch_bounds__(256)
void k_prep(const float* __restrict__ X,
            const float* __restrict__ Wq,
            const float* __restrict__ Wk,
            const float* __restrict__ Wv,
            unsigned short* __restrict__ Xb,
            unsigned short* __restrict__ Wt,
            float* __restrict__ zws){
  int blk = blockIdx.x, tid = threadIdx.x;
  if (blk < 4096){
    int i = (blk*256 + tid)*4;
    float4 v = *(const float4*)(X + i);
    ushort4v o; o.x = f2bf(v.x); o.y = f2bf(v.y); o.z = f2bf(v.z); o.w = f2bf(v.w);
    *(ushort4v*)(Xb + i) = o;
  } else {
    int o = (blk - 4096)*256 + tid;              // 0 .. 196607
    int p = o >> 16, rem = o & 65535;
    int j = rem >> 8, c = rem & 255;
    const float* W = (p==0) ? Wq : ((p==1) ? Wk : Wv);
    Wt[o] = f2bf(W[c*256 + j]);
    if (o < 5120) zws[o] = 0.f;                  // st (2048 f64) + sums (1KB)
  }
}

// --------------------------------------------------------------- QKV GEMM
// Y[t][n] = sum_c Xb[t][c] * Wt[n][c],  t<16384, n<768.
// Q/K planes (nb<8) written fragment-major fp32 into YQK; V (nb>=8) row-major
// into Yv. BN stats (sum, sumsq per channel) fused into the epilogue.
__global__ __launch_bounds__(256)
void k_qkv_gemm(const unsigned short* __restrict__ X,
                const unsigned short* __restrict__ Wt,
                float* __restrict__ YQK, float* __restrict__ Yv,
                double* __restrict__ st){
  __shared__ __align__(16) unsigned short At[64*264];
  __shared__ __align__(16) unsigned short Bt[64*264];
  int tid = threadIdx.x;
  int mb = blockIdx.x, nb = blockIdx.y;
#pragma unroll
  for (int it = 0; it < 8; ++it){
    int s = it*256 + tid;
    int row = s >> 5, ch = s & 31;
    uint4 a = *(const uint4*)(X  + ((size_t)(mb*64 + row))*256 + ch*8);
    uint4 b = *(const uint4*)(Wt + ((size_t)(nb*64 + row))*256 + ch*8);
    *(uint4*)(At + row*264 + ch*8) = a;
    *(uint4*)(Bt + row*264 + ch*8) = b;
  }
  __syncthreads();
  int lane = tid & 63, wv = tid >> 6;
  int ln15 = lane & 15, quad = lane >> 4;
  int rw = (wv & 1)*32, cw = (wv >> 1)*32;     // 2x2 waves, 32x32 each
  f32x4 acc[2][2] = {};
#pragma unroll
  for (int ks = 0; ks < 8; ++ks){
    short8 afr[2], bfr[2];
#pragma unroll
    for (int mt = 0; mt < 2; ++mt){
      int r = rw + mt*16 + ln15;
      afr[mt] = *(const short8*)(At + r*264 + (ks*4+quad)*8);
    }
#pragma unroll
    for (int nt = 0; nt < 2; ++nt){
      int r = cw + nt*16 + ln15;
      bfr[nt] = *(const short8*)(Bt + r*264 + (ks*4+quad)*8);
    }
#pragma unroll
    for (int mt = 0; mt < 2; ++mt)
#pragma unroll
      for (int nt = 0; nt < 2; ++nt)
        acc[mt][nt] = __builtin_amdgcn_mfma_f32_16x16x32_bf16(afr[mt], bfr[nt], acc[mt][nt], 0,0,0);
  }
  // ---- per-lane column partials for BN stats (raw Y values)
  float ps[2] = {0.f, 0.f}, pq[2] = {0.f, 0.f};
#pragma unroll
  for (int mt = 0; mt < 2; ++mt)
#pragma unroll
    for (int nt = 0; nt < 2; ++nt)
#pragma unroll
      for (int r = 0; r < 4; ++r){
        float v = acc[mt][nt][r];
        ps[nt] += v; pq[nt] += v*v;
      }
  // ---- C-store
  if (nb < 8){
    // fragment-major fp32: chunk = (g*16+ks)*64 + l5c*32 + l31r, elem j
    int proj = nb >> 2;
    float* base = YQK + (size_t)proj*(16384*256);
    int l5c = ln15 >> 3, j = ln15 & 7;
#pragma unroll
    for (int mt = 0; mt < 2; ++mt){
      int g = (mb*64 + rw + mt*16) >> 5;
      int l31r0 = ((rw + mt*16) & 31) + quad*4;
#pragma unroll
      for (int nt = 0; nt < 2; ++nt){
        int ks2 = ((nb & 3)*64 + cw + nt*16) >> 4;
#pragma unroll
        for (int r = 0; r < 4; ++r){
          size_t chunk = (size_t)((g*16 + ks2)*64 + l5c*32 + l31r0 + r);
          base[chunk*8 + j] = acc[mt][nt][r];
        }
      }
    }
  } else {
    int vc0 = (nb - 8)*64 + cw;
#pragma unroll
    for (int mt = 0; mt < 2; ++mt)
#pragma unroll
      for (int nt = 0; nt < 2; ++nt)
#pragma unroll
        for (int r = 0; r < 4; ++r){
          int row = mb*64 + rw + mt*16 + quad*4 + r;
          Yv[(size_t)row*256 + vc0 + nt*16 + ln15] = acc[mt][nt][r];
        }
  }
  // ---- stats reduce: LDS (reuse At) then one f64 atomic pair per channel
  __syncthreads();                       // everyone done reading At/Bt
  float* red = (float*)At;               // [0..64) sum, [64..128) sumsq
  if (tid < 128) red[tid] = 0.f;
  __syncthreads();
#pragma unroll
  for (int nt = 0; nt < 2; ++nt){
    int colL = cw + nt*16 + ln15;        // 0..63
    atomicAdd(&red[colL],      ps[nt]);
    atomicAdd(&red[64 + colL], pq[nt]);
  }
  __syncthreads();
  if (tid < 64){
    int cc = nb*64 + tid;                // global channel 0..767
    atomicAdd(&st[cc],       (double)red[tid]);
    atomicAdd(&st[768 + cc], (double)red[64 + tid]);
  }
}

// ------------------------------------------------- BN+leaky: Q,K frag stream
// + V transpose, one dispatch. Coefs computed inline from st (k_coef gone).
// blocks [0,4096): Q/K streaming path.  blocks [4096,5120): V path.
// Q coefs carry an extra 1/16 (score scale folded in; exact exponent shift).
__global__ __launch_bounds__(256)
void k_bn(const float* __restrict__ YQK, const float* __restrict__ Yv,
          const double* __restrict__ st,
          const float* __restrict__ gq, const float* __restrict__ bq,
          const float* __restrict__ gk, const float* __restrict__ bk,
          const float* __restrict__ gv, const float* __restrict__ bv,
          unsigned short* __restrict__ Qf, unsigned short* __restrict__ Kf,
          unsigned short* __restrict__ Vf){
  __shared__ float sc_s[256], sh_s[256];
  __shared__ unsigned short tile[64][66];
  int tid = threadIdx.x;
  int blk = blockIdx.x;
  if (blk < 4096){
    int proj = blk >> 11;                        // 2048 blocks per proj (0=Q,1=K)
    {
      int c = tid;
      int cc = proj*256 + c;
      double mu  = st[cc]     * (1.0/NTOT);
      double var = st[768+cc] * (1.0/NTOT) - mu*mu;
      double g = proj ? (double)gk[c] : (double)gq[c];
      double b = proj ? (double)bk[c] : (double)bq[c];
      double a = g / sqrt(var + EPS);
      float f = proj ? 1.f : 0.0625f;            // fold 1/16 into Q
      sc_s[c] = (float)a * f;
      sh_s[c] = (float)(b - mu*a) * f;
    }
    __syncthreads();
    int oc = blk*256 + tid;                      // chunk of 8 values
    int rest = oc & 524287;
    int ks = (rest >> 6) & 15, l5c = (rest >> 5) & 1;
    int ch0 = ks*16 + l5c*8;
    const float* src = YQK + (size_t)oc*8;
    float4 v0 = *(const float4*)(src);
    float4 v1 = *(const float4*)(src + 4);
    const float* sc = sc_s + ch0;
    const float* sh = sh_s + ch0;
    unsigned short r[8];
    r[0]=f2bf(lrelu(v0.x*sc[0]+sh[0])); r[1]=f2bf(lrelu(v0.y*sc[1]+sh[1]));
    r[2]=f2bf(lrelu(v0.z*sc[2]+sh[2])); r[3]=f2bf(lrelu(v0.w*sc[3]+sh[3]));
    r[4]=f2bf(lrelu(v1.x*sc[4]+sh[4])); r[5]=f2bf(lrelu(v1.y*sc[5]+sh[5]));
    r[6]=f2bf(lrelu(v1.z*sc[6]+sh[6])); r[7]=f2bf(lrelu(v1.w*sc[7]+sh[7]));
    uint4 u;
    u.x = (unsigned)r[0] | ((unsigned)r[1]<<16);
    u.y = (unsigned)r[2] | ((unsigned)r[3]<<16);
    u.z = (unsigned)r[4] | ((unsigned)r[5]<<16);
    u.w = (unsigned)r[6] | ((unsigned)r[7]<<16);
    *(uint4*)((proj ? Kf : Qf) + (size_t)rest*8) = u;
  } else {
    int b2 = blk - 4096;
    int pt = b2 & 63, ct = (b2 >> 6) & 3, b = b2 >> 8;
    if (tid < 64){
      int c = ct*64 + tid;
      int cc = 512 + c;
      double mu  = st[cc]     * (1.0/NTOT);
      double var = st[768+cc] * (1.0/NTOT) - mu*mu;
      double a = (double)gv[c] / sqrt(var + EPS);
      sc_s[tid] = (float)a;
      sh_s[tid] = (float)((double)bv[c] - mu*a);
    }
    __syncthreads();
    int cl = tid & 63, rq = tid >> 6;
    int c  = ct*64 + cl;
    float sc = sc_s[cl], sh = sh_s[cl];
#pragma unroll 4
    for (int k = 0; k < 16; ++k){
      int r = k*4 + rq;
      size_t t = (size_t)b*4096 + pt*64 + r;
      float v = Yv[t*256 + c];
      tile[r][cl] = f2bf(lrelu(v*sc + sh));
    }
    __syncthreads();
#pragma unroll
    for (int it = 0; it < 2; ++it){
      int m = it*256 + tid;                      // 512 chunks of 8 keys
      int c2 = m >> 3, kg = m & 7;
      int ch = ct*64 + c2;
      int gc = b*8 + (ch >> 5), l31c = ch & 31;
      int kp = pt*4 + (kg >> 1), l5k = kg & 1;
      unsigned short r0 = tile[kg*8+0][c2], r1 = tile[kg*8+1][c2];
      unsigned short r2 = tile[kg*8+2][c2], r3 = tile[kg*8+3][c2];
      unsigned short r4 = tile[kg*8+4][c2], r5 = tile[kg*8+5][c2];
      unsigned short r6 = tile[kg*8+6][c2], r7 = tile[kg*8+7][c2];
      uint4 u;
      u.x = (unsigned)r0 | ((unsigned)r1<<16);
      u.y = (unsigned)r2 | ((unsigned)r3<<16);
      u.z = (unsigned)r4 | ((unsigned)r5<<16);
      u.w = (unsigned)r6 | ((unsigned)r7<<16);
      *(uint4*)(Vf + ((size_t)((gc*256 + kp)*64 + l5k*32 + l31c))*8) = u;
    }
  }
}

// --------------------------------------------------------------- attention
// 512 blocks x 512 threads. blk>>3 = q-tile (64 rows), blk&7 = (b,half) ->
// XCD-pinned (round-robin dispatch) so each XCD's L2 holds its 2MB K/V.
// 8 iters of BK=256 keys, 2 barriers/iter. All global fragment loads are
// lane-contiguous 1KB (fragment-major layouts). Wave w: phase1 owns key
// group w*32 (computes both 32-row halves = 2 chains, no duplicate K reads);
// phase2 owns channels w*32..+32 (2 row-chain accumulators).
// setprio(1) wraps the MFMA phases (+7% measured R1). Score scale is folded
// into Q's BN coefs, so S-convert is just fmax+cvt.
__global__ __launch_bounds__(512, 4)
void k_attn(const unsigned short* __restrict__ Qf,
            const unsigned short* __restrict__ Kf,
            const unsigned short* __restrict__ Vf,
            float* __restrict__ P0, float* __restrict__ P1){
  __shared__ __align__(16) unsigned short Ql[64*256];   // frag-major Q tile
  __shared__ __align__(16) unsigned short Sl[64*264];   // [q][key] padded
  int tid = threadIdx.x;
  int blk = blockIdx.x;
  int qt = blk >> 3, combo = blk & 7;
  int b = combo >> 1, half = combo & 1;
  int q0 = qt*64;
  int lane = tid & 63, w = tid >> 6;
  int l31 = lane & 31, l5 = lane >> 5;
  float* P = half ? P1 : P0;

  // stage Q tile: contiguous 32KB copy (fragment-major, identity layout)
  int gq0 = b*128 + qt*2;
  {
    const uint4* src = (const uint4*)(Qf + (size_t)gq0*8192);
    uint4* dst = (uint4*)Ql;
#pragma unroll
    for (int it = 0; it < 4; ++it) dst[it*512 + tid] = src[it*512 + tid];
  }
  __syncthreads();

  f32x16 acc2[2] = {};
  // K frags: wave w owns keys [w*32, w*32+32) of each BK=256 chunk
  int gk0 = b*128 + half*64 + w;               // + kt*8 per iter
  const unsigned short* kb = Kf + (size_t)gk0*8192 + lane*8;
  // V frags: wave w owns channels [w*32, w*32+32)
  const unsigned short* vb = Vf + ((size_t)((b*8 + w)*256 + half*128))*512 + lane*8;
  const unsigned short* qa0 = Ql + lane*8;            // mloc 0, + ks*512
  const unsigned short* qa1 = Ql + 16*512 + lane*8;   // mloc 1

  for (int kt = 0; kt < 8; ++kt){
    // phase 1: S[0..64)[w*32..+32) over K=256, two independent row chains
    f32x16 a1[2] = {};
    const unsigned short* kbt = kb + (size_t)kt*8*8192;
    __builtin_amdgcn_s_setprio(1);
#pragma unroll
    for (int ks = 0; ks < 16; ++ks){
      short8 kf = *(const short8*)(kbt + ks*512);
      short8 q0v = *(const short8*)(qa0 + ks*512);
      short8 q1v = *(const short8*)(qa1 + ks*512);
      a1[0] = __builtin_amdgcn_mfma_f32_32x32x16_bf16(q0v, kf, a1[0], 0, 0, 0);
      a1[1] = __builtin_amdgcn_mfma_f32_32x32x16_bf16(q1v, kf, a1[1], 0, 0, 0);
    }
    __builtin_amdgcn_s_setprio(0);
    __syncthreads();     // B0: all waves done reading Sl of iter kt-1
#pragma unroll
    for (int reg = 0; reg < 16; ++reg){
      int rloc = (reg & 3) + 8*(reg >> 2) + 4*l5;
      float x0 = a1[0][reg], x1 = a1[1][reg];
      Sl[rloc*264 + w*32 + l31]        = f2bf(fmaxf(x0, 0.3f*x0));
      Sl[(32 + rloc)*264 + w*32 + l31] = f2bf(fmaxf(x1, 0.3f*x1));
    }
    __syncthreads();     // B1: S visible
    // phase 2: acc2 += S[64x256] . V^T[32ch][256keys]
    const unsigned short* vbt = vb + (size_t)kt*16*512;
    __builtin_amdgcn_s_setprio(1);
#pragma unroll
    for (int kk = 0; kk < 16; ++kk){
      short8 vf = *(const short8*)(vbt + kk*512);
      short8 s0 = *(const short8*)(Sl + (     l31)*264 + kk*16 + l5*8);
      short8 s1 = *(const short8*)(Sl + (32 + l31)*264 + kk*16 + l5*8);
      acc2[0] = __builtin_amdgcn_mfma_f32_32x32x16_bf16(s0, vf, acc2[0], 0, 0, 0);
      acc2[1] = __builtin_amdgcn_mfma_f32_32x32x16_bf16(s1, vf, acc2[1], 0, 0, 0);
    }
    __builtin_amdgcn_s_setprio(0);
  }
#pragma unroll
  for (int c = 0; c < 2; ++c)
#pragma unroll
    for (int reg = 0; reg < 16; ++reg){
      int row = q0 + c*32 + (reg & 3) + 8*(reg >> 2) + 4*l5;
      P[((size_t)b*4096 + row)*256 + w*32 + l31] = acc2[c][reg];
    }
}

// ------------------------------------------------- partial reduce + BN stats
// 512 blocks x 32 rows (full-grid BW; round-0 config)
__global__ __launch_bounds__(256)
void k_red(const float* __restrict__ P0, const float* __restrict__ P1,
           float* __restrict__ yout, double* __restrict__ st){
  int tid = threadIdx.x;
  int r0 = blockIdx.x*32;
  double sum = 0, sq = 0;
#pragma unroll 4
  for (int r = 0; r < 32; ++r){
    size_t idx = (size_t)(r0 + r)*256 + tid;
    float v = P0[idx] + P1[idx];
    yout[idx] = v;
    sum += v; sq += (double)v*v;
  }
  atomicAdd(&st[1536 + tid], sum);
  atomicAdd(&st[1792 + tid], sq);
}

// --------------------------------------------------------------- softmax
// BN => args are z-scores: no max pass needed; shift by a*mu.
__global__ __launch_bounds__(256)
void k_soft1(const float* __restrict__ yout, const double* __restrict__ st,
             const float* __restrict__ g1, float* __restrict__ sums){
  __shared__ float red[256];
  __shared__ float sA[64], sK[64];
  int tid = threadIdx.x;
  int chunk = blockIdx.x, ct = blockIdx.y, b = blockIdx.z;
  int cl = tid & 63, pg = tid >> 6;
  int c = ct*64 + cl;
  if (tid < 64){
    int cc = ct*64 + tid;
    double mu  = st[1536 + cc]*(1.0/NTOT);
    double var = st[1792 + cc]*(1.0/NTOT) - mu*mu;
    double a = g1[cc] / sqrt(var + EPS);
    sA[tid] = (float)a;
    sK[tid] = (float)(a*mu);
  }
  __syncthreads();
  float a = sA[cl], K = sK[cl];
  float s = 0.f;
  const float* base = yout + ((size_t)b*4096 + chunk*256)*256 + c;
#pragma unroll 4
  for (int k = 0; k < 64; ++k){
    float v = base[(size_t)(pg + k*4)*256];
    s += __expf(v*a - K);
  }
  red[tid] = s;
  __syncthreads();
  if (tid < 64){
    float tot = red[tid] + red[64+tid] + red[128+tid] + red[192+tid];
    atomicAdd(&sums[b*256 + ct*64 + tid], tot);
  }
}

__global__ __launch_bounds__(256)
void k_soft2(const float* __restrict__ yout, const double* __restrict__ st,
             const float* __restrict__ g1, const float* __restrict__ sums,
             float* __restrict__ out){
  __shared__ float sA[64], sK[64], sR[64];
  int tid = threadIdx.x;
  int chunk = blockIdx.x, ct = blockIdx.y, b = blockIdx.z;
  int cl = tid & 63, pg = tid >> 6;
  int c = ct*64 + cl;
  if (tid < 64){
    int cc = ct*64 + tid;
    double mu  = st[1536 + cc]*(1.0/NTOT);
    double var = st[1792 + cc]*(1.0/NTOT) - mu*mu;
    double a = g1[cc] / sqrt(var + EPS);
    sA[tid] = (float)a;
    sK[tid] = (float)(a*mu);
    sR[tid] = 1.f / sums[b*256 + cc];
  }
  __syncthreads();
  float a = sA[cl], K = sK[cl], rl = sR[cl];
  const float* base = yout + ((size_t)b*4096 + chunk*256)*256 + c;
  float* obase = out + ((size_t)b*4096 + chunk*256)*256 + c;
#pragma unroll 4
  for (int k = 0; k < 64; ++k){
    size_t idx = (size_t)(pg + k*4)*256;
    obase[idx] = __expf(base[idx]*a - K) * rl;
  }
}

// ---------------------------------------------------------------------------
extern "C" void kernel_launch(void* const* d_in, const int* in_sizes, int n_in,
                              void* d_out, int out_size, void* d_ws, size_t ws_size,
                              hipStream_t stream){
  (void)in_sizes; (void)n_in; (void)out_size; (void)ws_size;
  const float* X  = (const float*)d_in[0];
  const float* Wq = (const float*)d_in[1];
  const float* gq = (const float*)d_in[2];
  const float* bq = (const float*)d_in[3];
  const float* Wk = (const float*)d_in[4];
  const float* gk = (const float*)d_in[5];
  const float* bk = (const float*)d_in[6];
  const float* Wv = (const float*)d_in[7];
  const float* gv = (const float*)d_in[8];
  const float* bv = (const float*)d_in[9];
  const float* g1 = (const float*)d_in[10];
  // d_in[11] = b1: cancels inside the spatial softmax

  char* ws = (char*)d_ws;
  double*         st   = (double*)ws;                        // 2048 f64 (16KB)
  float*          sums = (float*)(ws + 16384);               // 4KB
  unsigned short* Wt   = (unsigned short*)(ws + 26624);      // 768x256 bf16
  unsigned short* Xb   = (unsigned short*)(ws + 419840);     // 16384x256 bf16
  float*          YQK  = (float*)(ws + 8808448);             // 2x16384x256 f32 (frag-major)
  float*          Yv   = (float*)(ws + 42362880);            // 16384x256 f32 row-major
  unsigned short* Kf   = (unsigned short*)(ws + 59140096);   // frag-major 8MB
  unsigned short* Vf   = (unsigned short*)(ws + 67528704);   // frag-major 8MB
  // overlays: Qf on Xb (dead after GEMM); P0|P1 on YQK (dead after bn);
  // yout on Yv (dead after bn)
  unsigned short* Qf   = Xb;
  float*          P0   = YQK;
  float*          P1   = (float*)((char*)YQK + 16777216);
  float*          yo   = Yv;

  k_prep    <<<4864, 256, 0, stream>>>(X, Wq, Wk, Wv, Xb, Wt, (float*)st);
  k_qkv_gemm<<<dim3(256,12), 256, 0, stream>>>(Xb, Wt, YQK, Yv, st);
  k_bn      <<<5120, 256, 0, stream>>>(YQK, Yv, st, gq, bq, gk, bk, gv, bv, Qf, Kf, Vf);
  k_attn    <<<512, 512, 0, stream>>>(Qf, Kf, Vf, P0, P1);
  k_red     <<<512, 256, 0, stream>>>(P0, P1, yo, st);
  k_soft1   <<<dim3(16,4,4), 256, 0, stream>>>(yo, st, g1, sums);
  k_soft2   <<<dim3(16,4,4), 256, 0, stream>>>(yo, st, g1, sums, (float*)d_out);
}

// Round 3
// 247.435 us; speedup vs baseline: 1.0216x; 1.0153x over previous
//
#include <hip/hip_runtime.h>
#include <stdint.h>

// ---------------------------------------------------------------------------
// GroupAttentionLayer: RF=16,STRIDE=16 windows tile the image exactly =>
//   yout = leaky(Q K^T / 16) V  (full dense attention per batch), then BN +
//   spatial softmax (mu/beta cancel; only a_c = g1/sqrt(var+eps) survives).
// B=4, P=4096 px/batch (T=16384 rows), C=256. Inputs fp32, OUTPUT fp32.
// R7: k_attn operands stored FRAGMENT-MAJOR in global so every MFMA fragment
//     load is a lane-contiguous 1KB dwordx4 from L2.
// R8: BN stats fused into GEMM epilogue; GEMM writes Q/K frag-major fp32 so
//     bn is pure streaming; setprio(1) around attn MFMA phases (+7%).
// R9: 7 dispatches; coefs inline; 1/16 folded into Q coefs.
// R10 (this round): k_attn q-tile 64 -> 128 rows/block (256 blocks).
//   Theory: attn was L2-BW-bound -- 512 blocks x (2MB K-half + 2MB V-half)
//   = 2GB L2 reads = 27 TB/s ~ 79% of the 34.5 TB/s ceiling. Halving the
//   block count halves K/V L2 traffic (1GB, floor ~29us) at unchanged MFMA
//   work; barriers per MFMA also halve. LDS 130KB (Ql 64K + Sl 66K) -> 1
//   block/CU, 2 waves/SIMD; a1[4]+acc2[4] ~170 VGPR < 256 cap @ 2 waves/EU.
//   Qf/Kf[((g*16+ks)*64+lane)*8+j] : row=g*32+(lane&31), ch=ks*16+(lane>>5)*8+j
//   Vf[((gc*256+kp)*64+lane)*8+j]  : ch=(gc&7)*32+(lane&31), key=kp*16+(lane>>5)*8+j
// ---------------------------------------------------------------------------

typedef __attribute__((ext_vector_type(8)))  short short8;   // 8 x bf16
typedef __attribute__((ext_vector_type(4)))  float f32x4;    // 16x16 acc
typedef __attribute__((ext_vector_type(16))) float f32x16;   // 32x32 acc
typedef __attribute__((ext_vector_type(4)))  unsigned short ushort4v;

#define ALPHA 0.3f
#define EPS   1e-3
#define NTOT  16384.0

__device__ __forceinline__ unsigned short f2bf(float f){
  unsigned u = __float_as_uint(f);
  u += 0x7FFFu + ((u>>16)&1u);          // RNE
  return (unsigned short)(u>>16);
}
__device__ __forceinline__ float lrelu(float x){ return fmaxf(x, ALPHA*x); }

// ------------------------------------------------- prep: cvt + wtrans + zero
__global__ __launch_bounds__(256)
void k_prep(const float* __restrict__ X,
            const float* __restrict__ Wq,
            const float* __restrict__ Wk,
            const float* __restrict__ Wv,
            unsigned short* __restrict__ Xb,
            unsigned short* __restrict__ Wt,
            float* __restrict__ zws){
  int blk = blockIdx.x, tid = threadIdx.x;
  if (blk < 4096){
    int i = (blk*256 + tid)*4;
    float4 v = *(const float4*)(X + i);
    ushort4v o; o.x = f2bf(v.x); o.y = f2bf(v.y); o.z = f2bf(v.z); o.w = f2bf(v.w);
    *(ushort4v*)(Xb + i) = o;
  } else {
    int o = (blk - 4096)*256 + tid;              // 0 .. 196607
    int p = o >> 16, rem = o & 65535;
    int j = rem >> 8, c = rem & 255;
    const float* W = (p==0) ? Wq : ((p==1) ? Wk : Wv);
    Wt[o] = f2bf(W[c*256 + j]);
    if (o < 5120) zws[o] = 0.f;                  // st (2048 f64) + sums (1KB)
  }
}

// --------------------------------------------------------------- QKV GEMM
__global__ __launch_bounds__(256)
void k_qkv_gemm(const unsigned short* __restrict__ X,
                const unsigned short* __restrict__ Wt,
                float* __restrict__ YQK, float* __restrict__ Yv,
                double* __restrict__ st){
  __shared__ __align__(16) unsigned short At[64*264];
  __shared__ __align__(16) unsigned short Bt[64*264];
  int tid = threadIdx.x;
  int mb = blockIdx.x, nb = blockIdx.y;
#pragma unroll
  for (int it = 0; it < 8; ++it){
    int s = it*256 + tid;
    int row = s >> 5, ch = s & 31;
    uint4 a = *(const uint4*)(X  + ((size_t)(mb*64 + row))*256 + ch*8);
    uint4 b = *(const uint4*)(Wt + ((size_t)(nb*64 + row))*256 + ch*8);
    *(uint4*)(At + row*264 + ch*8) = a;
    *(uint4*)(Bt + row*264 + ch*8) = b;
  }
  __syncthreads();
  int lane = tid & 63, wv = tid >> 6;
  int ln15 = lane & 15, quad = lane >> 4;
  int rw = (wv & 1)*32, cw = (wv >> 1)*32;     // 2x2 waves, 32x32 each
  f32x4 acc[2][2] = {};
#pragma unroll
  for (int ks = 0; ks < 8; ++ks){
    short8 afr[2], bfr[2];
#pragma unroll
    for (int mt = 0; mt < 2; ++mt){
      int r = rw + mt*16 + ln15;
      afr[mt] = *(const short8*)(At + r*264 + (ks*4+quad)*8);
    }
#pragma unroll
    for (int nt = 0; nt < 2; ++nt){
      int r = cw + nt*16 + ln15;
      bfr[nt] = *(const short8*)(Bt + r*264 + (ks*4+quad)*8);
    }
#pragma unroll
    for (int mt = 0; mt < 2; ++mt)
#pragma unroll
      for (int nt = 0; nt < 2; ++nt)
        acc[mt][nt] = __builtin_amdgcn_mfma_f32_16x16x32_bf16(afr[mt], bfr[nt], acc[mt][nt], 0,0,0);
  }
  // ---- per-lane column partials for BN stats (raw Y values)
  float ps[2] = {0.f, 0.f}, pq[2] = {0.f, 0.f};
#pragma unroll
  for (int mt = 0; mt < 2; ++mt)
#pragma unroll
    for (int nt = 0; nt < 2; ++nt)
#pragma unroll
      for (int r = 0; r < 4; ++r){
        float v = acc[mt][nt][r];
        ps[nt] += v; pq[nt] += v*v;
      }
  // ---- C-store
  if (nb < 8){
    int proj = nb >> 2;
    float* base = YQK + (size_t)proj*(16384*256);
    int l5c = ln15 >> 3, j = ln15 & 7;
#pragma unroll
    for (int mt = 0; mt < 2; ++mt){
      int g = (mb*64 + rw + mt*16) >> 5;
      int l31r0 = ((rw + mt*16) & 31) + quad*4;
#pragma unroll
      for (int nt = 0; nt < 2; ++nt){
        int ks2 = ((nb & 3)*64 + cw + nt*16) >> 4;
#pragma unroll
        for (int r = 0; r < 4; ++r){
          size_t chunk = (size_t)((g*16 + ks2)*64 + l5c*32 + l31r0 + r);
          base[chunk*8 + j] = acc[mt][nt][r];
        }
      }
    }
  } else {
    int vc0 = (nb - 8)*64 + cw;
#pragma unroll
    for (int mt = 0; mt < 2; ++mt)
#pragma unroll
      for (int nt = 0; nt < 2; ++nt)
#pragma unroll
        for (int r = 0; r < 4; ++r){
          int row = mb*64 + rw + mt*16 + quad*4 + r;
          Yv[(size_t)row*256 + vc0 + nt*16 + ln15] = acc[mt][nt][r];
        }
  }
  // ---- stats reduce: LDS (reuse At) then one f64 atomic pair per channel
  __syncthreads();
  float* red = (float*)At;               // [0..64) sum, [64..128) sumsq
  if (tid < 128) red[tid] = 0.f;
  __syncthreads();
#pragma unroll
  for (int nt = 0; nt < 2; ++nt){
    int colL = cw + nt*16 + ln15;        // 0..63
    atomicAdd(&red[colL],      ps[nt]);
    atomicAdd(&red[64 + colL], pq[nt]);
  }
  __syncthreads();
  if (tid < 64){
    int cc = nb*64 + tid;                // global channel 0..767
    atomicAdd(&st[cc],       (double)red[tid]);
    atomicAdd(&st[768 + cc], (double)red[64 + tid]);
  }
}

// ------------------------------------------------- BN+leaky: Q,K frag stream
// + V transpose, one dispatch. Coefs computed inline from st.
// Q coefs carry an extra 1/16 (score scale folded in; exact exponent shift).
__global__ __launch_bounds__(256)
void k_bn(const float* __restrict__ YQK, const float* __restrict__ Yv,
          const double* __restrict__ st,
          const float* __restrict__ gq, const float* __restrict__ bq,
          const float* __restrict__ gk, const float* __restrict__ bk,
          const float* __restrict__ gv, const float* __restrict__ bv,
          unsigned short* __restrict__ Qf, unsigned short* __restrict__ Kf,
          unsigned short* __restrict__ Vf){
  __shared__ float sc_s[256], sh_s[256];
  __shared__ unsigned short tile[64][66];
  int tid = threadIdx.x;
  int blk = blockIdx.x;
  if (blk < 4096){
    int proj = blk >> 11;                        // 2048 blocks per proj (0=Q,1=K)
    {
      int c = tid;
      int cc = proj*256 + c;
      double mu  = st[cc]     * (1.0/NTOT);
      double var = st[768+cc] * (1.0/NTOT) - mu*mu;
      double g = proj ? (double)gk[c] : (double)gq[c];
      double b = proj ? (double)bk[c] : (double)bq[c];
      double a = g / sqrt(var + EPS);
      float f = proj ? 1.f : 0.0625f;            // fold 1/16 into Q
      sc_s[c] = (float)a * f;
      sh_s[c] = (float)(b - mu*a) * f;
    }
    __syncthreads();
    int oc = blk*256 + tid;                      // chunk of 8 values
    int rest = oc & 524287;
    int ks = (rest >> 6) & 15, l5c = (rest >> 5) & 1;
    int ch0 = ks*16 + l5c*8;
    const float* src = YQK + (size_t)oc*8;
    float4 v0 = *(const float4*)(src);
    float4 v1 = *(const float4*)(src + 4);
    const float* sc = sc_s + ch0;
    const float* sh = sh_s + ch0;
    unsigned short r[8];
    r[0]=f2bf(lrelu(v0.x*sc[0]+sh[0])); r[1]=f2bf(lrelu(v0.y*sc[1]+sh[1]));
    r[2]=f2bf(lrelu(v0.z*sc[2]+sh[2])); r[3]=f2bf(lrelu(v0.w*sc[3]+sh[3]));
    r[4]=f2bf(lrelu(v1.x*sc[4]+sh[4])); r[5]=f2bf(lrelu(v1.y*sc[5]+sh[5]));
    r[6]=f2bf(lrelu(v1.z*sc[6]+sh[6])); r[7]=f2bf(lrelu(v1.w*sc[7]+sh[7]));
    uint4 u;
    u.x = (unsigned)r[0] | ((unsigned)r[1]<<16);
    u.y = (unsigned)r[2] | ((unsigned)r[3]<<16);
    u.z = (unsigned)r[4] | ((unsigned)r[5]<<16);
    u.w = (unsigned)r[6] | ((unsigned)r[7]<<16);
    *(uint4*)((proj ? Kf : Qf) + (size_t)rest*8) = u;
  } else {
    int b2 = blk - 4096;
    int pt = b2 & 63, ct = (b2 >> 6) & 3, b = b2 >> 8;
    if (tid < 64){
      int c = ct*64 + tid;
      int cc = 512 + c;
      double mu  = st[cc]     * (1.0/NTOT);
      double var = st[768+cc] * (1.0/NTOT) - mu*mu;
      double a = (double)gv[c] / sqrt(var + EPS);
      sc_s[tid] = (float)a;
      sh_s[tid] = (float)((double)bv[c] - mu*a);
    }
    __syncthreads();
    int cl = tid & 63, rq = tid >> 6;
    int c  = ct*64 + cl;
    float sc = sc_s[cl], sh = sh_s[cl];
#pragma unroll 4
    for (int k = 0; k < 16; ++k){
      int r = k*4 + rq;
      size_t t = (size_t)b*4096 + pt*64 + r;
      float v = Yv[t*256 + c];
      tile[r][cl] = f2bf(lrelu(v*sc + sh));
    }
    __syncthreads();
#pragma unroll
    for (int it = 0; it < 2; ++it){
      int m = it*256 + tid;                      // 512 chunks of 8 keys
      int c2 = m >> 3, kg = m & 7;
      int ch = ct*64 + c2;
      int gc = b*8 + (ch >> 5), l31c = ch & 31;
      int kp = pt*4 + (kg >> 1), l5k = kg & 1;
      unsigned short r0 = tile[kg*8+0][c2], r1 = tile[kg*8+1][c2];
      unsigned short r2 = tile[kg*8+2][c2], r3 = tile[kg*8+3][c2];
      unsigned short r4 = tile[kg*8+4][c2], r5 = tile[kg*8+5][c2];
      unsigned short r6 = tile[kg*8+6][c2], r7 = tile[kg*8+7][c2];
      uint4 u;
      u.x = (unsigned)r0 | ((unsigned)r1<<16);
      u.y = (unsigned)r2 | ((unsigned)r3<<16);
      u.z = (unsigned)r4 | ((unsigned)r5<<16);
      u.w = (unsigned)r6 | ((unsigned)r7<<16);
      *(uint4*)(Vf + ((size_t)((gc*256 + kp)*64 + l5k*32 + l31c))*8) = u;
    }
  }
}

// --------------------------------------------------------------- attention
// R10: 256 blocks x 512 threads, q-tile = 128 rows. blk>>3 = q-tile,
// blk&7 = (b,half) -> XCD-pinned (round-robin) so each XCD's L2 holds its
// 2MB K-half + 2MB V-half, now read by 32 blocks instead of 64 (L2 read
// traffic 2GB -> 1GB). 8 iters of BK=256 keys, 2 barriers/iter. Wave w:
// phase1 owns key group w*32 (4 row-chains = 128 q rows); phase2 owns
// channels w*32..+32 (4 row-chain accumulators). LDS 130KB -> 1 block/CU.
__global__ __launch_bounds__(512, 2)
void k_attn(const unsigned short* __restrict__ Qf,
            const unsigned short* __restrict__ Kf,
            const unsigned short* __restrict__ Vf,
            float* __restrict__ P0, float* __restrict__ P1){
  __shared__ __align__(16) unsigned short Ql[128*256];  // frag-major Q tile 64KB
  __shared__ __align__(16) unsigned short Sl[128*264];  // [q][key] padded 66KB
  int tid = threadIdx.x;
  int blk = blockIdx.x;
  int qt = blk >> 3, combo = blk & 7;
  int b = combo >> 1, half = combo & 1;
  int q0 = qt*128;
  int lane = tid & 63, w = tid >> 6;
  int l31 = lane & 31, l5 = lane >> 5;
  float* P = half ? P1 : P0;

  // stage Q tile: contiguous 64KB copy (fragment-major, identity layout)
  int gq0 = b*128 + qt*4;                        // 4 row-groups of 32
  {
    const uint4* src = (const uint4*)(Qf + (size_t)gq0*8192);
    uint4* dst = (uint4*)Ql;
#pragma unroll
    for (int it = 0; it < 8; ++it) dst[it*512 + tid] = src[it*512 + tid];
  }
  __syncthreads();

  f32x16 acc2[4] = {};
  // K frags: wave w owns keys [w*32, w*32+32) of each BK=256 chunk
  int gk0 = b*128 + half*64 + w;               // + kt*8 per iter
  const unsigned short* kb = Kf + (size_t)gk0*8192 + lane*8;
  // V frags: wave w owns channels [w*32, w*32+32)
  const unsigned short* vb = Vf + ((size_t)((b*8 + w)*256 + half*128))*512 + lane*8;
  const unsigned short* qa = Ql + lane*8;      // + m*8192 + ks*512

  for (int kt = 0; kt < 8; ++kt){
    // phase 1: S[0..128)[w*32..+32) over K=256, four independent row chains
    f32x16 a1[4] = {};
    const unsigned short* kbt = kb + (size_t)kt*8*8192;
    __builtin_amdgcn_s_setprio(1);
#pragma unroll
    for (int ks = 0; ks < 16; ++ks){
      short8 kf = *(const short8*)(kbt + ks*512);
      short8 q0v = *(const short8*)(qa +           ks*512);
      short8 q1v = *(const short8*)(qa +  8192   + ks*512);
      short8 q2v = *(const short8*)(qa +  16384  + ks*512);
      short8 q3v = *(const short8*)(qa +  24576  + ks*512);
      a1[0] = __builtin_amdgcn_mfma_f32_32x32x16_bf16(q0v, kf, a1[0], 0, 0, 0);
      a1[1] = __builtin_amdgcn_mfma_f32_32x32x16_bf16(q1v, kf, a1[1], 0, 0, 0);
      a1[2] = __builtin_amdgcn_mfma_f32_32x32x16_bf16(q2v, kf, a1[2], 0, 0, 0);
      a1[3] = __builtin_amdgcn_mfma_f32_32x32x16_bf16(q3v, kf, a1[3], 0, 0, 0);
    }
    __builtin_amdgcn_s_setprio(0);
    __syncthreads();     // B0: all waves done reading Sl of iter kt-1
#pragma unroll
    for (int reg = 0; reg < 16; ++reg){
      int rloc = (reg & 3) + 8*(reg >> 2) + 4*l5;
#pragma unroll
      for (int m = 0; m < 4; ++m){
        float x = a1[m][reg];
        Sl[(m*32 + rloc)*264 + w*32 + l31] = f2bf(fmaxf(x, 0.3f*x));
      }
    }
    __syncthreads();     // B1: S visible
    // phase 2: acc2 += S[128x256] . V^T[32ch][256keys]
    const unsigned short* vbt = vb + (size_t)kt*16*512;
    __builtin_amdgcn_s_setprio(1);
#pragma unroll
    for (int kk = 0; kk < 16; ++kk){
      short8 vf = *(const short8*)(vbt + kk*512);
      short8 s0 = *(const short8*)(Sl + (      l31)*264 + kk*16 + l5*8);
      short8 s1 = *(const short8*)(Sl + ( 32 + l31)*264 + kk*16 + l5*8);
      short8 s2 = *(const short8*)(Sl + ( 64 + l31)*264 + kk*16 + l5*8);
      short8 s3 = *(const short8*)(Sl + ( 96 + l31)*264 + kk*16 + l5*8);
      acc2[0] = __builtin_amdgcn_mfma_f32_32x32x16_bf16(s0, vf, acc2[0], 0, 0, 0);
      acc2[1] = __builtin_amdgcn_mfma_f32_32x32x16_bf16(s1, vf, acc2[1], 0, 0, 0);
      acc2[2] = __builtin_amdgcn_mfma_f32_32x32x16_bf16(s2, vf, acc2[2], 0, 0, 0);
      acc2[3] = __builtin_amdgcn_mfma_f32_32x32x16_bf16(s3, vf, acc2[3], 0, 0, 0);
    }
    __builtin_amdgcn_s_setprio(0);
  }
#pragma unroll
  for (int c = 0; c < 4; ++c)
#pragma unroll
    for (int reg = 0; reg < 16; ++reg){
      int row = q0 + c*32 + (reg & 3) + 8*(reg >> 2) + 4*l5;
      P[((size_t)b*4096 + row)*256 + w*32 + l31] = acc2[c][reg];
    }
}

// ------------------------------------------------- partial reduce + BN stats
__global__ __launch_bounds__(256)
void k_red(const float* __restrict__ P0, const float* __restrict__ P1,
           float* __restrict__ yout, double* __restrict__ st){
  int tid = threadIdx.x;
  int r0 = blockIdx.x*32;
  double sum = 0, sq = 0;
#pragma unroll 4
  for (int r = 0; r < 32; ++r){
    size_t idx = (size_t)(r0 + r)*256 + tid;
    float v = P0[idx] + P1[idx];
    yout[idx] = v;
    sum += v; sq += (double)v*v;
  }
  atomicAdd(&st[1536 + tid], sum);
  atomicAdd(&st[1792 + tid], sq);
}

// --------------------------------------------------------------- softmax
__global__ __launch_bounds__(256)
void k_soft1(const float* __restrict__ yout, const double* __restrict__ st,
             const float* __restrict__ g1, float* __restrict__ sums){
  __shared__ float red[256];
  __shared__ float sA[64], sK[64];
  int tid = threadIdx.x;
  int chunk = blockIdx.x, ct = blockIdx.y, b = blockIdx.z;
  int cl = tid & 63, pg = tid >> 6;
  int c = ct*64 + cl;
  if (tid < 64){
    int cc = ct*64 + tid;
    double mu  = st[1536 + cc]*(1.0/NTOT);
    double var = st[1792 + cc]*(1.0/NTOT) - mu*mu;
    double a = g1[cc] / sqrt(var + EPS);
    sA[tid] = (float)a;
    sK[tid] = (float)(a*mu);
  }
  __syncthreads();
  float a = sA[cl], K = sK[cl];
  float s = 0.f;
  const float* base = yout + ((size_t)b*4096 + chunk*256)*256 + c;
#pragma unroll 4
  for (int k = 0; k < 64; ++k){
    float v = base[(size_t)(pg + k*4)*256];
    s += __expf(v*a - K);
  }
  red[tid] = s;
  __syncthreads();
  if (tid < 64){
    float tot = red[tid] + red[64+tid] + red[128+tid] + red[192+tid];
    atomicAdd(&sums[b*256 + ct*64 + tid], tot);
  }
}

__global__ __launch_bounds__(256)
void k_soft2(const float* __restrict__ yout, const double* __restrict__ st,
             const float* __restrict__ g1, const float* __restrict__ sums,
             float* __restrict__ out){
  __shared__ float sA[64], sK[64], sR[64];
  int tid = threadIdx.x;
  int chunk = blockIdx.x, ct = blockIdx.y, b = blockIdx.z;
  int cl = tid & 63, pg = tid >> 6;
  int c = ct*64 + cl;
  if (tid < 64){
    int cc = ct*64 + tid;
    double mu  = st[1536 + cc]*(1.0/NTOT);
    double var = st[1792 + cc]*(1.0/NTOT) - mu*mu;
    double a = g1[cc] / sqrt(var + EPS);
    sA[tid] = (float)a;
    sK[tid] = (float)(a*mu);
    sR[tid] = 1.f / sums[b*256 + cc];
  }
  __syncthreads();
  float a = sA[cl], K = sK[cl], rl = sR[cl];
  const float* base = yout + ((size_t)b*4096 + chunk*256)*256 + c;
  float* obase = out + ((size_t)b*4096 + chunk*256)*256 + c;
#pragma unroll 4
  for (int k = 0; k < 64; ++k){
    size_t idx = (size_t)(pg + k*4)*256;
    obase[idx] = __expf(base[idx]*a - K) * rl;
  }
}

// ---------------------------------------------------------------------------
extern "C" void kernel_launch(void* const* d_in, const int* in_sizes, int n_in,
                              void* d_out, int out_size, void* d_ws, size_t ws_size,
                              hipStream_t stream){
  (void)in_sizes; (void)n_in; (void)out_size; (void)ws_size;
  const float* X  = (const float*)d_in[0];
  const float* Wq = (const float*)d_in[1];
  const float* gq = (const float*)d_in[2];
  const float* bq = (const float*)d_in[3];
  const float* Wk = (const float*)d_in[4];
  const float* gk = (const float*)d_in[5];
  const float* bk = (const float*)d_in[6];
  const float* Wv = (const float*)d_in[7];
  const float* gv = (const float*)d_in[8];
  const float* bv = (const float*)d_in[9];
  const float* g1 = (const float*)d_in[10];
  // d_in[11] = b1: cancels inside the spatial softmax

  char* ws = (char*)d_ws;
  double*         st   = (double*)ws;                        // 2048 f64 (16KB)
  float*          sums = (float*)(ws + 16384);               // 4KB
  unsigned short* Wt   = (unsigned short*)(ws + 26624);      // 768x256 bf16
  unsigned short* Xb   = (unsigned short*)(ws + 419840);     // 16384x256 bf16
  float*          YQK  = (float*)(ws + 8808448);             // 2x16384x256 f32 (frag-major)
  float*          Yv   = (float*)(ws + 42362880);            // 16384x256 f32 row-major
  unsigned short* Kf   = (unsigned short*)(ws + 59140096);   // frag-major 8MB
  unsigned short* Vf   = (unsigned short*)(ws + 67528704);   // frag-major 8MB
  // overlays: Qf on Xb (dead after GEMM); P0|P1 on YQK (dead after bn);
  // yout on Yv (dead after bn)
  unsigned short* Qf   = Xb;
  float*          P0   = YQK;
  float*          P1   = (float*)((char*)YQK + 16777216);
  float*          yo   = Yv;

  k_prep    <<<4864, 256, 0, stream>>>(X, Wq, Wk, Wv, Xb, Wt, (float*)st);
  k_qkv_gemm<<<dim3(256,12), 256, 0, stream>>>(Xb, Wt, YQK, Yv, st);
  k_bn      <<<5120, 256, 0, stream>>>(YQK, Yv, st, gq, bq, gk, bk, gv, bv, Qf, Kf, Vf);
  k_attn    <<<256, 512, 0, stream>>>(Qf, Kf, Vf, P0, P1);
  k_red     <<<512, 256, 0, stream>>>(P0, P1, yo, st);
  k_soft1   <<<dim3(16,4,4), 256, 0, stream>>>(yo, st, g1, sums);
  k_soft2   <<<dim3(16,4,4), 256, 0, stream>>>(yo, st, g1, sums, (float*)d_out);
}